// Round 1
// baseline (614.645 us; speedup 1.0000x reference)
//
#include <hip/hip_runtime.h>
#include <hip/hip_bf16.h>

#define BB 4
#define TT 256
#define UU 100
#define U1 101
#define VV 1024

__device__ __forceinline__ float lse2(float x, float y) {
    float m = fmaxf(x, y);
    float n = fminf(x, y);
    return m + __logf(1.0f + __expf(n - m));
}

// ---------------- Kernel 1: per-cell LSE over V, emit lp_blank/lp_emit transposed [b][u][t]
__global__ __launch_bounds__(256) void k_lse(const float* __restrict__ logits,
                                             const int* __restrict__ targets,
                                             float* __restrict__ lpB,
                                             float* __restrict__ lpE) {
    int wid  = (blockIdx.x << 2) | (threadIdx.x >> 6);   // one wave per cell
    int lane = threadIdx.x & 63;
    if (wid >= BB * TT * U1) return;
    // cell order: (b, t, u) with u fastest -> consecutive waves read contiguous logits
    int u  = wid % U1;
    int bt = wid / U1;
    int t  = bt % TT;
    int b  = bt / TT;
    const float* base = logits + (size_t)wid * VV;

    int tgt = targets[b * UU + min(u, UU - 1)];
    tgt = min(max(tgt, 0), VV - 1);
    float xb = base[0];      // blank logit (broadcast load)
    float xt = base[tgt];    // target logit

    const float4* b4 = (const float4*)base;
    float4 v0 = b4[lane];
    float4 v1 = b4[lane + 64];
    float4 v2 = b4[lane + 128];
    float4 v3 = b4[lane + 192];

    float m = fmaxf(fmaxf(fmaxf(v0.x, v0.y), fmaxf(v0.z, v0.w)),
                    fmaxf(fmaxf(v1.x, v1.y), fmaxf(v1.z, v1.w)));
    m = fmaxf(m, fmaxf(fmaxf(fmaxf(v2.x, v2.y), fmaxf(v2.z, v2.w)),
                       fmaxf(fmaxf(v3.x, v3.y), fmaxf(v3.z, v3.w))));
#pragma unroll
    for (int off = 32; off > 0; off >>= 1) m = fmaxf(m, __shfl_xor(m, off));

    float s = __expf(v0.x - m) + __expf(v0.y - m) + __expf(v0.z - m) + __expf(v0.w - m)
            + __expf(v1.x - m) + __expf(v1.y - m) + __expf(v1.z - m) + __expf(v1.w - m)
            + __expf(v2.x - m) + __expf(v2.y - m) + __expf(v2.z - m) + __expf(v2.w - m)
            + __expf(v3.x - m) + __expf(v3.y - m) + __expf(v3.z - m) + __expf(v3.w - m);
#pragma unroll
    for (int off = 32; off > 0; off >>= 1) s += __shfl_xor(s, off);

    float lse = m + __logf(s);
    if (lane == 0) {
        int o = (b * U1 + u) * TT + t;   // transposed [b][u][t]
        lpB[o] = xb - lse;
        if (u < UU) lpE[o] = xt - lse;
    }
}

// ---------------- Kernel 2: anti-diagonal wavefront DP, one wave per batch, 2 columns/lane
#define PF 8
__global__ __launch_bounds__(64) void k_dp(const float* __restrict__ lpB,
                                           const float* __restrict__ lpE,
                                           const int* __restrict__ tlen,
                                           const int* __restrict__ ulen,
                                           float* __restrict__ out) {
    const int b    = blockIdx.x;
    const int lane = threadIdx.x;
    const int Tb = tlen[b];
    const int Ub = ulen[b];
    const float* Bb = lpB + b * U1 * TT;
    const float* Eb = lpE + b * U1 * TT;
    const int u0 = lane * 2, u1 = u0 + 1;
    const float NEG = -1e30f;

    // clamped row bases (always land in rows kernel 1 actually wrote)
    const int rB0 = min(u0, U1 - 1) * TT;
    const int rB1 = min(u1, U1 - 1) * TT;
    const int rE0 = min(max(u0 - 1, 0), UU - 1) * TT;
    const int rE1 = min(u0, UU - 1) * TT;

    auto cl = [](int x) { return x < 0 ? 0 : (x > TT - 1 ? TT - 1 : x); };

    float aLo = (lane == 0) ? 0.0f : NEG;   // alpha(0,0)=0 at diagonal 0
    float aHi = NEG;
    float aHiLeft = NEG;                    // shfl of all-NEG initial aHi

    float fB0[PF], fB1[PF], fE0[PF], fE1[PF];
#pragma unroll
    for (int j = 0; j < PF; ++j) {
        int d = 1 + j;
        fB0[j] = Bb[rB0 + cl(d - 1 - u0)];
        fB1[j] = Bb[rB1 + cl(d - 1 - u1)];
        fE0[j] = Eb[rE0 + cl(d - u0)];
        fE1[j] = Eb[rE1 + cl(d - 1 - u0)];
    }

    const int D = Tb - 1 + Ub;              // last diagonal
    for (int dbase = 1; dbase <= D; dbase += PF) {
#pragma unroll
        for (int j = 0; j < PF; ++j) {
            const int d = dbase + j;
            float B0 = fB0[j], B1 = fB1[j], E0 = fE0[j], E1 = fE1[j];
            // prefetch PF diagonals ahead (addresses alpha-independent)
            const int dn = d + PF;
            fB0[j] = Bb[rB0 + cl(dn - 1 - u0)];
            fB1[j] = Bb[rB1 + cl(dn - 1 - u1)];
            fE0[j] = Eb[rE0 + cl(dn - u0)];
            fE1[j] = Eb[rE1 + cl(dn - 1 - u0)];

            float t1lo = aLo + B0;                                  // blank from (t-1,u0)
            float t2lo = (lane == 0) ? NEG : aHiLeft + E0;          // emit from (t,u0-1)
            float t1hi = aHi + B1;                                  // blank from (t-1,u1)
            float t2hi = aLo + E1;                                  // emit from (t,u0) [prev-diag aLo]

            bool okLo = (u0 <= Ub) && (d >= u0) && (d <= u0 + Tb - 1);
            bool okHi = (u1 <= Ub) && (d >= u1) && (d <= u1 + Tb - 1);

            float nLo = lse2(t1lo, t2lo);
            float nHi = lse2(t1hi, t2hi);
            aLo = okLo ? nLo : aLo;
            aHi = okHi ? nHi : aHi;
            aHiLeft = __shfl_up(aHi, 1);    // for next diagonal's lo cell
        }
    }

    if (u0 == Ub || u1 == Ub) {
        float aF = (u0 == Ub) ? aLo : aHi;
        out[b] = -(aF + Bb[min(Ub, U1 - 1) * TT + (Tb - 1)]);
    }
}

extern "C" void kernel_launch(void* const* d_in, const int* in_sizes, int n_in,
                              void* d_out, int out_size, void* d_ws, size_t ws_size,
                              hipStream_t stream) {
    const float* logits = (const float*)d_in[0];
    const int* targets  = (const int*)d_in[1];
    const int* tlen     = (const int*)d_in[2];
    const int* ulen     = (const int*)d_in[3];
    float* out = (float*)d_out;

    float* lpB = (float*)d_ws;                       // B*U1*T floats
    float* lpE = lpB + (size_t)BB * U1 * TT;         // B*U1*T floats

    int cells = BB * TT * U1;
    int blocks = (cells + 3) / 4;                    // 4 waves (cells) per 256-thread block
    k_lse<<<blocks, 256, 0, stream>>>(logits, targets, lpB, lpE);
    k_dp<<<BB, 64, 0, stream>>>(lpB, lpE, tlen, ulen, out);
}